// Round 9
// baseline (151.280 us; speedup 1.0000x reference)
//
#include <hip/hip_runtime.h>
#include <math.h>

#define BB 16
#define PP 4096
#define TT 1024
#define JT 16
#define QTR 1024           // preds per block-quarter (P split in 4)
#define NBLK (BB * 16 * 4) // 1024 blocks
#define LIMKEY 0x41C80FFFu // key <= this  <=>  quantized d2 <= 25.0f (0x41C80000)

// Single fused kernel. Grid: 1024 blocks = 16 b x 16 target-tiles x 4 P-quarters,
// 256 thr = 4 waves, wave owns 16 targets scanning its 1024-pred quarter.
// Class-island encoding: x' = fma(cls,128,x) -> cross-class d2 >= 4096, rejected by
// the deferred radius test; no per-pair class compare. Packed key
// (d2_bits & ~0xFFF) | p -> argmin + lowest-p tie-break via one v_min_u32.
// Tail: last-arriving block (device-scope ticket + release/acquire fences) min-
// combines the 4 quarters, radius-filters, bitmaps distinct hit preds in LDS,
// popcounts -> tp, writes the F1 loss scalar.
__global__ __launch_bounds__(256) void fused_kernel(const float* __restrict__ pred,
                                                    const float* __restrict__ gt,
                                                    unsigned* __restrict__ part,
                                                    unsigned* __restrict__ ticket,
                                                    float* __restrict__ out) {
    const int blk   = blockIdx.x;
    const int b     = blk >> 6;           // 64 blocks per batch
    const int ttile = (blk >> 2) & 15;    // 64 targets per block
    const int qtr   = blk & 3;
    const int wave  = threadIdx.x >> 6;   // 0..3
    const int lane  = threadIdx.x & 63;
    const int tbase = ttile * 64 + wave * JT;
    const int pbase = qtr * QTR;

    // ---- match phase ----
    const float* gb = gt + ((size_t)(b * TT + tbase)) * 3;
    float gx[JT], gy[JT];
    unsigned key[JT];
    #pragma unroll
    for (int j = 0; j < JT; ++j) {
        const float c = gb[j * 3 + 0];
        gx[j] = fmaf(c, 128.0f, gb[j * 3 + 1]);   // island offset by class
        gy[j] = gb[j * 3 + 2];
        key[j] = 0xFFFFFFFFu;
    }

    const float* pl = pred + (size_t)b * PP * 3 + (size_t)(pbase + lane) * 3;

    #pragma unroll 4
    for (int i = 0; i < QTR / 64; ++i) {
        const float pc = pl[0];
        const float px = pl[1];
        const float py = pl[2];
        pl += 192;
        const float pxp = fmaf(pc, 128.0f, px);
        const unsigned po = (unsigned)(pbase + (i << 6) + lane);
        #pragma unroll
        for (int j = 0; j < JT; ++j) {
            const float dx = pxp - gx[j];
            const float dy = py - gy[j];
            const float d2 = fmaf(dx, dx, dy * dy);
            const unsigned kk = (__float_as_uint(d2) & 0xFFFFF000u) | po;
            key[j] = min(key[j], kk);
        }
    }

    for (int off = 32; off; off >>= 1) {
        #pragma unroll
        for (int j = 0; j < JT; ++j) {
            const unsigned o = __shfl_down(key[j], off, 64);
            key[j] = min(key[j], o);
        }
    }

    if (lane == 0) {
        #pragma unroll
        for (int j = 0; j < JT; ++j)
            part[(size_t)qtr * (BB * TT) + b * TT + tbase + j] = key[j];
    }

    // ---- last-block tail ----
    __shared__ int is_last;
    __threadfence();                        // release part writes (device scope)
    if (threadIdx.x == 0)
        is_last = (atomicAdd(ticket, 1u) == NBLK - 1);
    __syncthreads();
    if (!is_last) return;
    __threadfence();                        // acquire all blocks' part writes

    __shared__ unsigned bm[BB * PP / 32];   // 2048 words = 8 KB
    for (int i = threadIdx.x; i < BB * PP / 32; i += 256) bm[i] = 0;
    __syncthreads();

    for (int i = threadIdx.x; i < BB * TT; i += 256) {
        const unsigned k = min(min(part[i],              part[BB * TT + i]),
                               min(part[2 * BB * TT + i], part[3 * BB * TT + i]));
        if (k <= LIMKEY) {
            const unsigned g = (unsigned)(i >> 10) * PP + (k & 0xFFFu);
            atomicOr(&bm[g >> 5], 1u << (g & 31));
        }
    }
    __syncthreads();

    int sum = 0;
    for (int i = threadIdx.x; i < BB * PP / 32; i += 256) sum += __popc(bm[i]);
    for (int off = 32; off; off >>= 1) sum += __shfl_down(sum, off, 64);

    __shared__ int ss[4];
    if (lane == 0) ss[wave] = sum;
    __syncthreads();
    if (threadIdx.x == 0) {
        const float tp = (float)(ss[0] + ss[1] + ss[2] + ss[3]);
        const float eps = 1e-6f;
        const float fp = (float)(BB * PP) - tp;
        const float fn = (float)(BB * TT) - tp;
        const float precision = (tp + eps) / (tp + eps + fp + eps);
        const float recall    = (tp + eps) / (tp + fn + eps);
        const float f1 = 2.0f * precision * recall / (precision + recall);
        out[0] = 1.0f - f1;
    }
}

extern "C" void kernel_launch(void* const* d_in, const int* in_sizes, int n_in,
                              void* d_out, int out_size, void* d_ws, size_t ws_size,
                              hipStream_t stream) {
    const float* pred = (const float*)d_in[0];  // (B, P, 3): cls, x, y
    const float* gt   = (const float*)d_in[1];  // (B, T, 3)
    float* out = (float*)d_out;

    unsigned* part   = (unsigned*)d_ws;                      // 4 * B*T u32 = 256 KB
    unsigned* ticket = (unsigned*)((char*)d_ws + 4 * BB * TT * 4);

    hipMemsetAsync(ticket, 0, 4, stream);
    fused_kernel<<<NBLK, 256, 0, stream>>>(pred, gt, part, ticket, out);
}

// Round 10
// 72.313 us; speedup vs baseline: 2.0920x; 2.0920x over previous
//
#include <hip/hip_runtime.h>
#include <math.h>

#define BB 16
#define PP 4096
#define TT 1024
#define JT 16
#define QTR 1024           // preds per block (P split in 4 quarters)
#define LIMKEY 0x41C80FFFu // key <= this  <=>  quantized d2 <= 25.0f (0x41C80000)

// Grid: 1024 blocks = 16 b x 16 target-tiles x 4 P-quarters. Block = 256 thr = 4 waves.
// Each wave owns 16 targets, scans its 1024-pred quarter (lane = p mod 64).
// Class-island encoding: x' = fma(cls, 128, x) -> cross-class d2 >= 4096, auto-
// rejected by deferred radius test; no per-pair class compare. Packed key
// (d2_bits & ~0xFFF) | p gives argmin + lowest-p tie-break via one v_min_u32.
// Inner loop = 6 VALU/pair. part[qtr][b*TT+t] fully written -> no ws init.
// NO fences: the kernel boundary is the coherence point (R9 lesson: __threadfence
// wbl2/inv storms cost ~85 us across 1024 blocks).
__global__ __launch_bounds__(256) void match_kernel(const float* __restrict__ pred,
                                                    const float* __restrict__ gt,
                                                    unsigned* __restrict__ part) {
    const int blk   = blockIdx.x;
    const int b     = blk >> 6;           // 64 blocks per batch
    const int ttile = (blk >> 2) & 15;    // 64 targets per block
    const int qtr   = blk & 3;
    const int wave  = threadIdx.x >> 6;   // 0..3
    const int lane  = threadIdx.x & 63;
    const int tbase = ttile * 64 + wave * JT;
    const int pbase = qtr * QTR;

    const float* gb = gt + ((size_t)(b * TT + tbase)) * 3;
    float gx[JT], gy[JT];
    unsigned key[JT];
    #pragma unroll
    for (int j = 0; j < JT; ++j) {
        const float c = gb[j * 3 + 0];
        gx[j] = fmaf(c, 128.0f, gb[j * 3 + 1]);   // island offset by class
        gy[j] = gb[j * 3 + 2];
        key[j] = 0xFFFFFFFFu;
    }

    const float* pl = pred + (size_t)b * PP * 3 + (size_t)(pbase + lane) * 3;

    #pragma unroll 4
    for (int i = 0; i < QTR / 64; ++i) {
        const float pc = pl[0];
        const float px = pl[1];
        const float py = pl[2];
        pl += 192;
        const float pxp = fmaf(pc, 128.0f, px);
        const unsigned po = (unsigned)(pbase + (i << 6) + lane);
        #pragma unroll
        for (int j = 0; j < JT; ++j) {
            const float dx = pxp - gx[j];
            const float dy = py - gy[j];
            const float d2 = fmaf(dx, dx, dy * dy);
            const unsigned kk = (__float_as_uint(d2) & 0xFFFFF000u) | po;
            key[j] = min(key[j], kk);
        }
    }

    for (int off = 32; off; off >>= 1) {
        #pragma unroll
        for (int j = 0; j < JT; ++j) {
            const unsigned o = __shfl_down(key[j], off, 64);
            key[j] = min(key[j], o);
        }
    }

    if (lane == 0) {
        #pragma unroll
        for (int j = 0; j < JT; ++j)
            part[(size_t)qtr * (BB * TT) + b * TT + tbase + j] = key[j];
    }
}

// Single block, 1024 thr: min-combine the 4 quarters per target, radius-filter,
// bitmap distinct hit preds (8 KB LDS, all batches), popcount -> tp, F1 scalar.
__global__ __launch_bounds__(1024) void tail_kernel(const unsigned* __restrict__ part,
                                                    float* __restrict__ out) {
    __shared__ unsigned bm[BB * PP / 32];   // 2048 words = 8 KB
    for (int i = threadIdx.x; i < BB * PP / 32; i += 1024) bm[i] = 0;
    __syncthreads();

    #pragma unroll 4
    for (int i = threadIdx.x; i < BB * TT; i += 1024) {
        const unsigned k = min(min(part[i],               part[BB * TT + i]),
                               min(part[2 * BB * TT + i], part[3 * BB * TT + i]));
        if (k <= LIMKEY) {
            const unsigned g = (unsigned)(i >> 10) * PP + (k & 0xFFFu);
            atomicOr(&bm[g >> 5], 1u << (g & 31));
        }
    }
    __syncthreads();

    int sum = 0;
    for (int i = threadIdx.x; i < BB * PP / 32; i += 1024) sum += __popc(bm[i]);
    for (int off = 32; off; off >>= 1) sum += __shfl_down(sum, off, 64);

    __shared__ int ss[16];
    const int wid  = threadIdx.x >> 6;
    const int lane = threadIdx.x & 63;
    if (lane == 0) ss[wid] = sum;
    __syncthreads();
    if (threadIdx.x == 0) {
        int tp_i = 0;
        for (int w = 0; w < 16; ++w) tp_i += ss[w];
        const float tp = (float)tp_i;
        const float eps = 1e-6f;
        const float fp = (float)(BB * PP) - tp;
        const float fn = (float)(BB * TT) - tp;
        const float precision = (tp + eps) / (tp + eps + fp + eps);
        const float recall    = (tp + eps) / (tp + fn + eps);
        const float f1 = 2.0f * precision * recall / (precision + recall);
        out[0] = 1.0f - f1;
    }
}

extern "C" void kernel_launch(void* const* d_in, const int* in_sizes, int n_in,
                              void* d_out, int out_size, void* d_ws, size_t ws_size,
                              hipStream_t stream) {
    const float* pred = (const float*)d_in[0];  // (B, P, 3): cls, x, y
    const float* gt   = (const float*)d_in[1];  // (B, T, 3)
    float* out = (float*)d_out;
    unsigned* part = (unsigned*)d_ws;           // 4 * B*T u32 = 256 KB

    match_kernel<<<BB * 16 * 4, 256, 0, stream>>>(pred, gt, part);
    tail_kernel<<<1, 1024, 0, stream>>>(part, out);
}

// Round 11
// 71.100 us; speedup vs baseline: 2.1277x; 1.0171x over previous
//
#include <hip/hip_runtime.h>
#include <math.h>

#define BB 16
#define PP 4096
#define TT 1024
#define JT 16
#define QTR 1024           // preds per block (P split in 4 quarters)
#define LIMKEY 0x41C80FFFu // key <= this  <=>  quantized d2 <= 25.0f (0x41C80000)

// Phase 0: AoS (cls,x,y) -> SoA planes with class-island fold at rest:
// xp = fma(cls, 128, x)  (cross-class pairs get d2 >= 4096 -> radius-rejected).
// Each thread owns 4 triples: 3 float4 loads, 2 float4 stores, all dense.
__global__ __launch_bounds__(256) void transpose_kernel(const float* __restrict__ pred,
                                                        const float* __restrict__ gt,
                                                        float* __restrict__ pred_xp,
                                                        float* __restrict__ pred_y,
                                                        float* __restrict__ tgt_xp,
                                                        float* __restrict__ tgt_y) {
    const int blk = blockIdx.x;
    const float4* src;
    float4* dxp; float4* dy;
    int t;
    if (blk < 64) {            // preds: 16384 threads x 4 triples
        t = blk * 256 + threadIdx.x;
        src = (const float4*)pred;
        dxp = (float4*)pred_xp; dy = (float4*)pred_y;
    } else {                   // targets: 4096 threads x 4 triples
        t = (blk - 64) * 256 + threadIdx.x;
        src = (const float4*)gt;
        dxp = (float4*)tgt_xp;  dy = (float4*)tgt_y;
    }
    const float4 v0 = src[3 * t + 0];
    const float4 v1 = src[3 * t + 1];
    const float4 v2 = src[3 * t + 2];
    // triples: (v0.x v0.y v0.z)(v0.w v1.x v1.y)(v1.z v1.w v2.x)(v2.y v2.z v2.w)
    float4 xp, yy;
    xp.x = fmaf(v0.x, 128.0f, v0.y);  yy.x = v0.z;
    xp.y = fmaf(v0.w, 128.0f, v1.x);  yy.y = v1.y;
    xp.z = fmaf(v1.z, 128.0f, v1.w);  yy.z = v2.x;
    xp.w = fmaf(v2.y, 128.0f, v2.z);  yy.w = v2.w;
    dxp[t] = xp;
    dy[t]  = yy;
}

// Phase 1: 1024 blocks = 16 b x 16 target-tiles x 4 P-quarters; 4 waves/block,
// wave owns 16 targets. float4 SoA loads: 4 preds/thread/iter, 2 VMEM per
// 256-pred chunk. Per pair: sub, sub, fma, v_and_or_b32, v_min_u32 = 5 VALU.
// Packed key (d2_bits & ~0xFFF) | p -> argmin + lowest-p tie-break.
// part[qtr][b*TT+t] fully written -> no ws init. No fences (R9 lesson).
__global__ __launch_bounds__(256) void match_kernel(const float* __restrict__ pred_xp,
                                                    const float* __restrict__ pred_y,
                                                    const float* __restrict__ tgt_xp,
                                                    const float* __restrict__ tgt_y,
                                                    unsigned* __restrict__ part) {
    const int blk   = blockIdx.x;
    const int b     = blk >> 6;           // 64 blocks per batch
    const int ttile = (blk >> 2) & 15;    // 64 targets per block
    const int qtr   = blk & 3;
    const int wave  = threadIdx.x >> 6;   // 0..3
    const int lane  = threadIdx.x & 63;
    const int tbase = ttile * 64 + wave * JT;
    const int pbase = qtr * QTR;

    float gx[JT], gy[JT];
    unsigned key[JT];
    {
        const float4* gx4 = (const float4*)(tgt_xp + b * TT + tbase);
        const float4* gy4 = (const float4*)(tgt_y  + b * TT + tbase);
        #pragma unroll
        for (int j4 = 0; j4 < JT / 4; ++j4) {
            const float4 a = gx4[j4], c = gy4[j4];
            gx[j4 * 4 + 0] = a.x; gx[j4 * 4 + 1] = a.y; gx[j4 * 4 + 2] = a.z; gx[j4 * 4 + 3] = a.w;
            gy[j4 * 4 + 0] = c.x; gy[j4 * 4 + 1] = c.y; gy[j4 * 4 + 2] = c.z; gy[j4 * 4 + 3] = c.w;
        }
    }
    #pragma unroll
    for (int j = 0; j < JT; ++j) key[j] = 0xFFFFFFFFu;

    const float4* xp4 = (const float4*)(pred_xp + (size_t)b * PP + pbase);
    const float4* yy4 = (const float4*)(pred_y  + (size_t)b * PP + pbase);

    #pragma unroll
    for (int i = 0; i < QTR / 256; ++i) {
        const int idx = i * 64 + lane;
        const float4 xv = xp4[idx];
        const float4 yv = yy4[idx];
        const unsigned po0 = (unsigned)(pbase + idx * 4);
        const float pxs[4] = {xv.x, xv.y, xv.z, xv.w};
        const float pys[4] = {yv.x, yv.y, yv.z, yv.w};
        #pragma unroll
        for (int k = 0; k < 4; ++k) {
            const float px = pxs[k];
            const float py = pys[k];
            const unsigned po = po0 + k;
            #pragma unroll
            for (int j = 0; j < JT; ++j) {
                const float dx = px - gx[j];
                const float dy = py - gy[j];
                const float d2 = fmaf(dx, dx, dy * dy);
                const unsigned kk = (__float_as_uint(d2) & 0xFFFFF000u) | po;
                key[j] = min(key[j], kk);
            }
        }
    }

    for (int off = 32; off; off >>= 1) {
        #pragma unroll
        for (int j = 0; j < JT; ++j) {
            const unsigned o = __shfl_down(key[j], off, 64);
            key[j] = min(key[j], o);
        }
    }

    if (lane == 0) {
        #pragma unroll
        for (int j = 0; j < JT; ++j)
            part[(size_t)qtr * (BB * TT) + b * TT + tbase + j] = key[j];
    }
}

// Phase 2: single block, 1024 thr: min-combine 4 quarters per target, radius-
// filter, bitmap distinct hit preds (8 KB LDS), popcount -> tp, F1 scalar.
__global__ __launch_bounds__(1024) void tail_kernel(const unsigned* __restrict__ part,
                                                    float* __restrict__ out) {
    __shared__ unsigned bm[BB * PP / 32];   // 2048 words = 8 KB
    for (int i = threadIdx.x; i < BB * PP / 32; i += 1024) bm[i] = 0;
    __syncthreads();

    #pragma unroll 4
    for (int i = threadIdx.x; i < BB * TT; i += 1024) {
        const unsigned k = min(min(part[i],               part[BB * TT + i]),
                               min(part[2 * BB * TT + i], part[3 * BB * TT + i]));
        if (k <= LIMKEY) {
            const unsigned g = (unsigned)(i >> 10) * PP + (k & 0xFFFu);
            atomicOr(&bm[g >> 5], 1u << (g & 31));
        }
    }
    __syncthreads();

    int sum = 0;
    for (int i = threadIdx.x; i < BB * PP / 32; i += 1024) sum += __popc(bm[i]);
    for (int off = 32; off; off >>= 1) sum += __shfl_down(sum, off, 64);

    __shared__ int ss[16];
    const int wid  = threadIdx.x >> 6;
    const int lane = threadIdx.x & 63;
    if (lane == 0) ss[wid] = sum;
    __syncthreads();
    if (threadIdx.x == 0) {
        int tp_i = 0;
        for (int w = 0; w < 16; ++w) tp_i += ss[w];
        const float tp = (float)tp_i;
        const float eps = 1e-6f;
        const float fp = (float)(BB * PP) - tp;
        const float fn = (float)(BB * TT) - tp;
        const float precision = (tp + eps) / (tp + eps + fp + eps);
        const float recall    = (tp + eps) / (tp + fn + eps);
        const float f1 = 2.0f * precision * recall / (precision + recall);
        out[0] = 1.0f - f1;
    }
}

extern "C" void kernel_launch(void* const* d_in, const int* in_sizes, int n_in,
                              void* d_out, int out_size, void* d_ws, size_t ws_size,
                              hipStream_t stream) {
    const float* pred = (const float*)d_in[0];  // (B, P, 3): cls, x, y
    const float* gt   = (const float*)d_in[1];  // (B, T, 3)
    float* out = (float*)d_out;

    char* ws = (char*)d_ws;
    float*    pred_xp = (float*)(ws + 0);        // 256 KB
    float*    pred_y  = (float*)(ws + 262144);   // 256 KB
    float*    tgt_xp  = (float*)(ws + 524288);   // 64 KB
    float*    tgt_y   = (float*)(ws + 589824);   // 64 KB
    unsigned* part    = (unsigned*)(ws + 655360);// 256 KB

    transpose_kernel<<<80, 256, 0, stream>>>(pred, gt, pred_xp, pred_y, tgt_xp, tgt_y);
    match_kernel<<<BB * 16 * 4, 256, 0, stream>>>(pred_xp, pred_y, tgt_xp, tgt_y, part);
    tail_kernel<<<1, 1024, 0, stream>>>(part, out);
}